// Round 2
// baseline (1080.583 us; speedup 1.0000x reference)
//
#include <hip/hip_runtime.h>

#define EXP 8
#define DM 1024
#define DH 4096
#define NT 16384

typedef __attribute__((ext_vector_type(8))) short bf16x8;
typedef __attribute__((ext_vector_type(4))) float f32x4;

static __device__ __forceinline__ unsigned short f2bf(float f) {
  unsigned int u = __float_as_uint(f);
  u = u + 0x7FFFu + ((u >> 16) & 1u);
  return (unsigned short)(u >> 16);
}

static __device__ __forceinline__ void gload_lds16(const void* g, void* l) {
  __builtin_amdgcn_global_load_lds((const __attribute__((address_space(1))) void*)g,
                                   (__attribute__((address_space(3))) void*)l, 16, 0, 0);
}

// swizzled LDS element index for a [*][64] bf16 tile: XOR the 16B-chunk index
// (col>>3) with (row&7).  Pairs with pre-swizzled global source (rule #21).
static __device__ __forceinline__ int swz_idx(int r, int kk) {
  return r * 64 + (((kk >> 3) ^ (r & 7)) << 3);
}

// ---- X fp32 -> bf16 (same layout) ----
__global__ void cvt_bf16_k(const float* __restrict__ in, unsigned short* __restrict__ out,
                           long n4) {
  long i = (long)blockIdx.x * blockDim.x + threadIdx.x;
  const long stride = (long)gridDim.x * blockDim.x;
  for (; i < n4; i += stride) {
    const float4 v = ((const float4*)in)[i];
    ushort4 o;
    o.x = f2bf(v.x); o.y = f2bf(v.y); o.z = f2bf(v.z); o.w = f2bf(v.w);
    ((ushort4*)out)[i] = o;
  }
}

// ---- [B][K][N] fp32 -> [B][N][K] bf16 ----
__global__ void transpose_cvt(const float* __restrict__ in, unsigned short* __restrict__ out,
                              int K, int N) {
  __shared__ float tile[32][33];
  const int n0 = blockIdx.x * 32, k0 = blockIdx.y * 32;
  const size_t boff = (size_t)blockIdx.z * K * N;
  const int tx = threadIdx.x, ty = threadIdx.y;
  const float* src = in + boff;
  unsigned short* dst = out + boff;
#pragma unroll
  for (int i = 0; i < 32; i += 8)
    tile[ty + i][tx] = src[(size_t)(k0 + ty + i) * N + n0 + tx];
  __syncthreads();
#pragma unroll
  for (int i = 0; i < 32; i += 8)
    dst[(size_t)(n0 + ty + i) * K + k0 + tx] = f2bf(tile[tx][ty + i]);
}

// ---- GEMM1: H = gelu(X@Wg) * (X@Wl + b_lin), bf16 out ----
// X: [NT][DM] bf16 row-major; WgT/WlT: [E][DH][DM] bf16 (n-major, k-contig)
__global__ __launch_bounds__(256, 3) void gemm1(
    const unsigned short* __restrict__ Xb,
    const unsigned short* __restrict__ WgT,
    const unsigned short* __restrict__ WlT,
    const float* __restrict__ b_lin,
    unsigned short* __restrict__ Hb) {
  __shared__ unsigned short sA[128 * 64];
  __shared__ unsigned short sBg[128 * 64];
  __shared__ unsigned short sBl[128 * 64];

  const int t = threadIdx.x;
  const int nblk = blockIdx.x, mblk = blockIdx.y;
  const int e = mblk >> 4;               // 2048 tokens per expert, 16 m-blocks each
  const int m0 = mblk * 128, n0 = nblk * 128;

  const int lane = t & 63;
  const int wave = t >> 6;
  const int wr = wave >> 1, wc = wave & 1;  // 2x2 waves, 64x64 each
  const int lrow = lane & 15;
  const int lk8 = (lane >> 4) * 8;

  const int srow = t >> 3;        // staging: 32 rows per call, 8x16B chunks per row
  const int schunk = t & 7;
  // pre-swizzled global chunk (row&7 == srow&7 since row-step is 32)
  const int ssw = ((schunk ^ (srow & 7)) << 3);

  const unsigned short* gA = Xb + (size_t)m0 * DM + ssw;
  const unsigned short* gG = WgT + (size_t)e * DH * DM + (size_t)n0 * DM + ssw;
  const unsigned short* gL = WlT + (size_t)e * DH * DM + (size_t)n0 * DM + ssw;

  f32x4 accg[4][4], accl[4][4];
#pragma unroll
  for (int i = 0; i < 4; i++)
#pragma unroll
    for (int j = 0; j < 4; j++) { accg[i][j] = 0.0f; accl[i][j] = 0.0f; }

  for (int kt = 0; kt < DM / 64; ++kt) {
    const int k0 = kt * 64;
#pragma unroll
    for (int c = 0; c < 4; c++) {
      const int row = c * 32 + srow;
      gload_lds16(gA + (size_t)row * DM + k0, (char*)sA + row * 128 + schunk * 16);
      gload_lds16(gG + (size_t)row * DM + k0, (char*)sBg + row * 128 + schunk * 16);
      gload_lds16(gL + (size_t)row * DM + k0, (char*)sBl + row * 128 + schunk * 16);
    }
    __syncthreads();
#pragma unroll
    for (int ks = 0; ks < 2; ks++) {
      const int kk = ks * 32 + lk8;
      bf16x8 af[4], bg[4], bl[4];
#pragma unroll
      for (int i = 0; i < 4; i++)
        af[i] = *(const bf16x8*)&sA[swz_idx(wr * 64 + i * 16 + lrow, kk)];
#pragma unroll
      for (int j = 0; j < 4; j++) {
        bg[j] = *(const bf16x8*)&sBg[swz_idx(wc * 64 + j * 16 + lrow, kk)];
        bl[j] = *(const bf16x8*)&sBl[swz_idx(wc * 64 + j * 16 + lrow, kk)];
      }
#pragma unroll
      for (int i = 0; i < 4; i++)
#pragma unroll
        for (int j = 0; j < 4; j++) {
          accg[i][j] = __builtin_amdgcn_mfma_f32_16x16x32_bf16(af[i], bg[j], accg[i][j], 0, 0, 0);
          accl[i][j] = __builtin_amdgcn_mfma_f32_16x16x32_bf16(af[i], bl[j], accl[i][j], 0, 0, 0);
        }
    }
    __syncthreads();
  }

  // epilogue: h = gelu_tanh(g) * (l + bias), write bf16
  const float* bl_p = b_lin + (size_t)e * DH;
  const int r0 = (lane >> 4) * 4;
#pragma unroll
  for (int i = 0; i < 4; i++) {
    const int grow = m0 + wr * 64 + i * 16 + r0;
#pragma unroll
    for (int j = 0; j < 4; j++) {
      const int gcol = n0 + wc * 64 + j * 16 + lrow;
      const float bias = bl_p[gcol];
#pragma unroll
      for (int r = 0; r < 4; r++) {
        const float g = accg[i][j][r];
        const float li = accl[i][j][r] + bias;
        const float u = 0.7978845608028654f * (g + 0.044715f * g * g * g);
        const float th = 1.0f - 2.0f / (1.0f + __expf(2.0f * u));
        const float h = 0.5f * g * (1.0f + th) * li;
        Hb[(size_t)(grow + r) * DH + gcol] = f2bf(h);
      }
    }
  }
}

// ---- GEMM2: out = H @ Wo + b_o, fp32 out ----
// H: [NT][DH] bf16; WoT: [E][DM][DH] bf16 (n-major, k-contig)
__global__ __launch_bounds__(256, 4) void gemm2(
    const unsigned short* __restrict__ Hb,
    const unsigned short* __restrict__ WoT,
    const float* __restrict__ b_o,
    float* __restrict__ out) {
  __shared__ unsigned short sA[128 * 64];
  __shared__ unsigned short sB[128 * 64];

  const int t = threadIdx.x;
  const int nblk = blockIdx.x, mblk = blockIdx.y;
  const int e = mblk >> 4;
  const int m0 = mblk * 128, n0 = nblk * 128;

  const int lane = t & 63;
  const int wave = t >> 6;
  const int wr = wave >> 1, wc = wave & 1;
  const int lrow = lane & 15;
  const int lk8 = (lane >> 4) * 8;

  const int srow = t >> 3;
  const int schunk = t & 7;
  const int ssw = ((schunk ^ (srow & 7)) << 3);

  const unsigned short* gA = Hb + (size_t)m0 * DH + ssw;
  const unsigned short* gB = WoT + (size_t)e * DM * DH + (size_t)n0 * DH + ssw;

  f32x4 acc[4][4];
#pragma unroll
  for (int i = 0; i < 4; i++)
#pragma unroll
    for (int j = 0; j < 4; j++) acc[i][j] = 0.0f;

  for (int kt = 0; kt < DH / 64; ++kt) {
    const int k0 = kt * 64;
#pragma unroll
    for (int c = 0; c < 4; c++) {
      const int row = c * 32 + srow;
      gload_lds16(gA + (size_t)row * DH + k0, (char*)sA + row * 128 + schunk * 16);
      gload_lds16(gB + (size_t)row * DH + k0, (char*)sB + row * 128 + schunk * 16);
    }
    __syncthreads();
#pragma unroll
    for (int ks = 0; ks < 2; ks++) {
      const int kk = ks * 32 + lk8;
      bf16x8 af[4], bf[4];
#pragma unroll
      for (int i = 0; i < 4; i++)
        af[i] = *(const bf16x8*)&sA[swz_idx(wr * 64 + i * 16 + lrow, kk)];
#pragma unroll
      for (int j = 0; j < 4; j++)
        bf[j] = *(const bf16x8*)&sB[swz_idx(wc * 64 + j * 16 + lrow, kk)];
#pragma unroll
      for (int i = 0; i < 4; i++)
#pragma unroll
        for (int j = 0; j < 4; j++)
          acc[i][j] = __builtin_amdgcn_mfma_f32_16x16x32_bf16(af[i], bf[j], acc[i][j], 0, 0, 0);
    }
    __syncthreads();
  }

  const float* bo_p = b_o + (size_t)e * DM;
  const int r0 = (lane >> 4) * 4;
#pragma unroll
  for (int i = 0; i < 4; i++) {
    const int grow = m0 + wr * 64 + i * 16 + r0;
#pragma unroll
    for (int j = 0; j < 4; j++) {
      const int gcol = n0 + wc * 64 + j * 16 + lrow;
      const float bias = bo_p[gcol];
#pragma unroll
      for (int r = 0; r < 4; r++)
        out[(size_t)(grow + r) * DM + gcol] = acc[i][j][r] + bias;
    }
  }
}

extern "C" void kernel_launch(void* const* d_in, const int* in_sizes, int n_in,
                              void* d_out, int out_size, void* d_ws, size_t ws_size,
                              hipStream_t stream) {
  const float* hs = (const float*)d_in[0];
  // d_in[1] = fwd_expert_count: equal groups of NT/EXP by construction, unused
  const float* w_gelu = (const float*)d_in[2];
  const float* w_lin = (const float*)d_in[3];
  const float* b_lin = (const float*)d_in[4];
  const float* w_o = (const float*)d_in[5];
  const float* b_o = (const float*)d_in[6];
  float* outp = (float*)d_out;

  // workspace layout (bf16 elements): Xb | WgT | WlT | WoT | Hb  (total ~352 MB)
  unsigned short* Xb = (unsigned short*)d_ws;
  unsigned short* WgT = Xb + (size_t)NT * DM;
  unsigned short* WlT = WgT + (size_t)EXP * DH * DM;
  unsigned short* WoT = WlT + (size_t)EXP * DH * DM;
  unsigned short* Hb = WoT + (size_t)EXP * DH * DM;

  cvt_bf16_k<<<dim3(2048), dim3(256), 0, stream>>>(hs, Xb, (long)NT * DM / 4);
  // Wg, Wl: [E][DM][DH] -> [E][DH][DM]
  transpose_cvt<<<dim3(DH / 32, DM / 32, EXP), dim3(32, 8), 0, stream>>>(w_gelu, WgT, DM, DH);
  transpose_cvt<<<dim3(DH / 32, DM / 32, EXP), dim3(32, 8), 0, stream>>>(w_lin, WlT, DM, DH);
  // Wo: [E][DH][DM] -> [E][DM][DH]
  transpose_cvt<<<dim3(DM / 32, DH / 32, EXP), dim3(32, 8), 0, stream>>>(w_o, WoT, DH, DM);

  gemm1<<<dim3(DH / 128, NT / 128), dim3(256), 0, stream>>>(Xb, WgT, WlT, b_lin, Hb);
  gemm2<<<dim3(DM / 128, NT / 128), dim3(256), 0, stream>>>(Hb, WoT, b_o, outp);
}

// Round 3
// 634.243 us; speedup vs baseline: 1.7037x; 1.7037x over previous
//
#include <hip/hip_runtime.h>

#define EXP 8
#define DM 1024
#define DH 4096
#define NT 16384

typedef __attribute__((ext_vector_type(8))) short bf16x8;
typedef __attribute__((ext_vector_type(4))) float f32x4;

static __device__ __forceinline__ unsigned short f2bf(float f) {
  unsigned int u = __float_as_uint(f);
  u = u + 0x7FFFu + ((u >> 16) & 1u);
  return (unsigned short)(u >> 16);
}

static __device__ __forceinline__ void gload_lds16(const void* g, void* l) {
  __builtin_amdgcn_global_load_lds((const __attribute__((address_space(1))) void*)g,
                                   (__attribute__((address_space(3))) void*)l, 16, 0, 0);
}

// swizzled LDS element index for a [*][64] bf16 tile: XOR the 16B-chunk index
// (col>>3) with (row&7).  Pairs with pre-swizzled global source (rule #21).
static __device__ __forceinline__ int swz_idx(int r, int kk) {
  return r * 64 + (((kk >> 3) ^ (r & 7)) << 3);
}

// ---- X fp32 -> bf16 (same layout) ----
__global__ void cvt_bf16_k(const float* __restrict__ in, unsigned short* __restrict__ out,
                           long n4) {
  long i = (long)blockIdx.x * blockDim.x + threadIdx.x;
  const long stride = (long)gridDim.x * blockDim.x;
  for (; i < n4; i += stride) {
    const float4 v = ((const float4*)in)[i];
    ushort4 o;
    o.x = f2bf(v.x); o.y = f2bf(v.y); o.z = f2bf(v.z); o.w = f2bf(v.w);
    ((ushort4*)out)[i] = o;
  }
}

// ---- [B][K][N] fp32 -> [B][N][K] bf16 ----
__global__ void transpose_cvt(const float* __restrict__ in, unsigned short* __restrict__ out,
                              int K, int N) {
  __shared__ float tile[32][33];
  const int n0 = blockIdx.x * 32, k0 = blockIdx.y * 32;
  const size_t boff = (size_t)blockIdx.z * K * N;
  const int tx = threadIdx.x, ty = threadIdx.y;
  const float* src = in + boff;
  unsigned short* dst = out + boff;
#pragma unroll
  for (int i = 0; i < 32; i += 8)
    tile[ty + i][tx] = src[(size_t)(k0 + ty + i) * N + n0 + tx];
  __syncthreads();
#pragma unroll
  for (int i = 0; i < 32; i += 8)
    dst[(size_t)(n0 + ty + i) * K + k0 + tx] = f2bf(tile[tx][ty + i]);
}

// ---- GEMM1: H = gelu(X@Wg) * (X@Wl + b_lin), bf16 out ----
// X: [NT][DM] bf16 row-major; WgT/WlT: [E][DH][DM] bf16 (n-major, k-contig)
// launch_bounds(256,2): 128 accumulator regs need the 256-reg/wave budget;
// (256,3) spilled acc to scratch (round 2: WRITE_SIZE 131->735 MB, 2x slower).
__global__ __launch_bounds__(256, 2) void gemm1(
    const unsigned short* __restrict__ Xb,
    const unsigned short* __restrict__ WgT,
    const unsigned short* __restrict__ WlT,
    const float* __restrict__ b_lin,
    unsigned short* __restrict__ Hb) {
  __shared__ unsigned short sA[128 * 64];
  __shared__ unsigned short sBg[128 * 64];
  __shared__ unsigned short sBl[128 * 64];

  const int t = threadIdx.x;
  const int nblk = blockIdx.x, mblk = blockIdx.y;
  const int e = mblk >> 4;               // 2048 tokens per expert, 16 m-blocks each
  const int m0 = mblk * 128, n0 = nblk * 128;

  const int lane = t & 63;
  const int wave = t >> 6;
  const int wr = wave >> 1, wc = wave & 1;  // 2x2 waves, 64x64 each
  const int lrow = lane & 15;
  const int lk8 = (lane >> 4) * 8;

  const int srow = t >> 3;        // staging: 32 rows per call, 8x16B chunks per row
  const int schunk = t & 7;
  // pre-swizzled global chunk (row&7 == srow&7 since row-step is 32)
  const int ssw = ((schunk ^ (srow & 7)) << 3);

  const unsigned short* gA = Xb + (size_t)m0 * DM + ssw;
  const unsigned short* gG = WgT + (size_t)e * DH * DM + (size_t)n0 * DM + ssw;
  const unsigned short* gL = WlT + (size_t)e * DH * DM + (size_t)n0 * DM + ssw;

  f32x4 accg[4][4], accl[4][4];
#pragma unroll
  for (int i = 0; i < 4; i++)
#pragma unroll
    for (int j = 0; j < 4; j++) { accg[i][j] = 0.0f; accl[i][j] = 0.0f; }

  for (int kt = 0; kt < DM / 64; ++kt) {
    const int k0 = kt * 64;
#pragma unroll
    for (int c = 0; c < 4; c++) {
      const int row = c * 32 + srow;
      gload_lds16(gA + (size_t)row * DM + k0, (char*)sA + row * 128 + schunk * 16);
      gload_lds16(gG + (size_t)row * DM + k0, (char*)sBg + row * 128 + schunk * 16);
      gload_lds16(gL + (size_t)row * DM + k0, (char*)sBl + row * 128 + schunk * 16);
    }
    __syncthreads();
#pragma unroll
    for (int ks = 0; ks < 2; ks++) {
      const int kk = ks * 32 + lk8;
      bf16x8 af[4], bg[4], bl[4];
#pragma unroll
      for (int i = 0; i < 4; i++)
        af[i] = *(const bf16x8*)&sA[swz_idx(wr * 64 + i * 16 + lrow, kk)];
#pragma unroll
      for (int j = 0; j < 4; j++) {
        bg[j] = *(const bf16x8*)&sBg[swz_idx(wc * 64 + j * 16 + lrow, kk)];
        bl[j] = *(const bf16x8*)&sBl[swz_idx(wc * 64 + j * 16 + lrow, kk)];
      }
#pragma unroll
      for (int i = 0; i < 4; i++)
#pragma unroll
        for (int j = 0; j < 4; j++) {
          accg[i][j] = __builtin_amdgcn_mfma_f32_16x16x32_bf16(af[i], bg[j], accg[i][j], 0, 0, 0);
          accl[i][j] = __builtin_amdgcn_mfma_f32_16x16x32_bf16(af[i], bl[j], accl[i][j], 0, 0, 0);
        }
    }
    __syncthreads();
  }

  // epilogue: h = gelu_tanh(g) * (l + bias), write bf16
  const float* bl_p = b_lin + (size_t)e * DH;
  const int r0 = (lane >> 4) * 4;
#pragma unroll
  for (int i = 0; i < 4; i++) {
    const int grow = m0 + wr * 64 + i * 16 + r0;
#pragma unroll
    for (int j = 0; j < 4; j++) {
      const int gcol = n0 + wc * 64 + j * 16 + lrow;
      const float bias = bl_p[gcol];
#pragma unroll
      for (int r = 0; r < 4; r++) {
        const float g = accg[i][j][r];
        const float li = accl[i][j][r] + bias;
        const float u = 0.7978845608028654f * (g + 0.044715f * g * g * g);
        const float th = 1.0f - 2.0f / (1.0f + __expf(2.0f * u));
        const float h = 0.5f * g * (1.0f + th) * li;
        Hb[(size_t)(grow + r) * DH + gcol] = f2bf(h);
      }
    }
  }
}

// ---- GEMM2: out = H @ Wo + b_o, fp32 out ----
// H: [NT][DH] bf16; WoT: [E][DM][DH] bf16 (n-major, k-contig)
// (256,3): 64 acc regs + ~50 working < 170 budget, no spill; 32KB LDS -> 3 blocks/CU.
__global__ __launch_bounds__(256, 3) void gemm2(
    const unsigned short* __restrict__ Hb,
    const unsigned short* __restrict__ WoT,
    const float* __restrict__ b_o,
    float* __restrict__ out) {
  __shared__ unsigned short sA[128 * 64];
  __shared__ unsigned short sB[128 * 64];

  const int t = threadIdx.x;
  const int nblk = blockIdx.x, mblk = blockIdx.y;
  const int e = mblk >> 4;
  const int m0 = mblk * 128, n0 = nblk * 128;

  const int lane = t & 63;
  const int wave = t >> 6;
  const int wr = wave >> 1, wc = wave & 1;
  const int lrow = lane & 15;
  const int lk8 = (lane >> 4) * 8;

  const int srow = t >> 3;
  const int schunk = t & 7;
  const int ssw = ((schunk ^ (srow & 7)) << 3);

  const unsigned short* gA = Hb + (size_t)m0 * DH + ssw;
  const unsigned short* gB = WoT + (size_t)e * DM * DH + (size_t)n0 * DH + ssw;

  f32x4 acc[4][4];
#pragma unroll
  for (int i = 0; i < 4; i++)
#pragma unroll
    for (int j = 0; j < 4; j++) acc[i][j] = 0.0f;

  for (int kt = 0; kt < DH / 64; ++kt) {
    const int k0 = kt * 64;
#pragma unroll
    for (int c = 0; c < 4; c++) {
      const int row = c * 32 + srow;
      gload_lds16(gA + (size_t)row * DH + k0, (char*)sA + row * 128 + schunk * 16);
      gload_lds16(gB + (size_t)row * DH + k0, (char*)sB + row * 128 + schunk * 16);
    }
    __syncthreads();
#pragma unroll
    for (int ks = 0; ks < 2; ks++) {
      const int kk = ks * 32 + lk8;
      bf16x8 af[4], bf[4];
#pragma unroll
      for (int i = 0; i < 4; i++)
        af[i] = *(const bf16x8*)&sA[swz_idx(wr * 64 + i * 16 + lrow, kk)];
#pragma unroll
      for (int j = 0; j < 4; j++)
        bf[j] = *(const bf16x8*)&sB[swz_idx(wc * 64 + j * 16 + lrow, kk)];
#pragma unroll
      for (int i = 0; i < 4; i++)
#pragma unroll
        for (int j = 0; j < 4; j++)
          acc[i][j] = __builtin_amdgcn_mfma_f32_16x16x32_bf16(af[i], bf[j], acc[i][j], 0, 0, 0);
    }
    __syncthreads();
  }

  const float* bo_p = b_o + (size_t)e * DM;
  const int r0 = (lane >> 4) * 4;
#pragma unroll
  for (int i = 0; i < 4; i++) {
    const int grow = m0 + wr * 64 + i * 16 + r0;
#pragma unroll
    for (int j = 0; j < 4; j++) {
      const int gcol = n0 + wc * 64 + j * 16 + lrow;
      const float bias = bo_p[gcol];
#pragma unroll
      for (int r = 0; r < 4; r++)
        out[(size_t)(grow + r) * DM + gcol] = acc[i][j][r] + bias;
    }
  }
}

extern "C" void kernel_launch(void* const* d_in, const int* in_sizes, int n_in,
                              void* d_out, int out_size, void* d_ws, size_t ws_size,
                              hipStream_t stream) {
  const float* hs = (const float*)d_in[0];
  // d_in[1] = fwd_expert_count: equal groups of NT/EXP by construction, unused
  const float* w_gelu = (const float*)d_in[2];
  const float* w_lin = (const float*)d_in[3];
  const float* b_lin = (const float*)d_in[4];
  const float* w_o = (const float*)d_in[5];
  const float* b_o = (const float*)d_in[6];
  float* outp = (float*)d_out;

  // workspace layout (bf16 elements): Xb | WgT | WlT | WoT | Hb  (total ~352 MB)
  unsigned short* Xb = (unsigned short*)d_ws;
  unsigned short* WgT = Xb + (size_t)NT * DM;
  unsigned short* WlT = WgT + (size_t)EXP * DH * DM;
  unsigned short* WoT = WlT + (size_t)EXP * DH * DM;
  unsigned short* Hb = WoT + (size_t)EXP * DH * DM;

  cvt_bf16_k<<<dim3(2048), dim3(256), 0, stream>>>(hs, Xb, (long)NT * DM / 4);
  // Wg, Wl: [E][DM][DH] -> [E][DH][DM]
  transpose_cvt<<<dim3(DH / 32, DM / 32, EXP), dim3(32, 8), 0, stream>>>(w_gelu, WgT, DM, DH);
  transpose_cvt<<<dim3(DH / 32, DM / 32, EXP), dim3(32, 8), 0, stream>>>(w_lin, WlT, DM, DH);
  // Wo: [E][DH][DM] -> [E][DM][DH]
  transpose_cvt<<<dim3(DM / 32, DH / 32, EXP), dim3(32, 8), 0, stream>>>(w_o, WoT, DH, DM);

  gemm1<<<dim3(DH / 128, NT / 128), dim3(256), 0, stream>>>(Xb, WgT, WlT, b_lin, Hb);
  gemm2<<<dim3(DM / 128, NT / 128), dim3(256), 0, stream>>>(Hb, WoT, b_o, outp);
}